// Round 6
// baseline (636.164 us; speedup 1.0000x reference)
//
#include <hip/hip_runtime.h>
#include <hip/hip_bf16.h>
#include <stdint.h>

#define B_  2
#define S_  4096
#define D_  1024
#define FF_ 4096
#define E_  8
#define C_  1024

typedef unsigned short u16;
typedef unsigned int   u32;
typedef float f32x4  __attribute__((ext_vector_type(4)));
typedef short bf16x8 __attribute__((ext_vector_type(8)));
typedef u16   u16x8  __attribute__((ext_vector_type(8)));

static __device__ __forceinline__ u16 f2bf(float f) {
    union { float f; u32 u; } v; v.f = f;
    u32 u = v.u;
    u32 r = (u + 0x7FFFu + ((u >> 16) & 1u)) >> 16;  // RNE; inputs are finite
    return (u16)r;
}

static __device__ __forceinline__ void gload_lds16(const u16* g, u16* l) {
    __builtin_amdgcn_global_load_lds(
        (const __attribute__((address_space(1))) u32*)g,
        (__attribute__((address_space(3))) u32*)l, 16, 0, 0);
}

// ============ transpose + convert: [K][N] fp32 -> [N][K] bf16, per expert ============
__global__ __launch_bounds__(256) void transpose_cvt(const float* __restrict__ src,
                                                     u16* __restrict__ dst, int K, int N) {
    __shared__ u16 t[64 * 64];
    size_t mat = (size_t)blockIdx.z * K * N;
    int n0 = blockIdx.x * 64, k0 = blockIdx.y * 64;
    int l = threadIdx.x & 63, w = threadIdx.x >> 6;
#pragma unroll
    for (int p = 0; p < 2; ++p) {
        int k = p * 32 + w * 8 + ((l >> 4) << 1);     // even k
        int n = (l & 15) * 4;
        float4 v0 = *(const float4*)&src[mat + (size_t)(k0 + k) * N + n0 + n];
        float4 v1 = *(const float4*)&src[mat + (size_t)(k0 + k + 1) * N + n0 + n];
        float a0[4] = {v0.x, v0.y, v0.z, v0.w};
        float a1[4] = {v1.x, v1.y, v1.z, v1.w};
#pragma unroll
        for (int j = 0; j < 4; ++j) {
            int nn = n + j;
            u32 pk = (u32)f2bf(a0[j]) | ((u32)f2bf(a1[j]) << 16);
            int slot = (k >> 3) ^ ((nn & 7) ^ ((nn >> 3) & 7));
            *(u32*)((char*)t + nn * 128 + slot * 16 + (k & 7) * 2) = pk;
        }
    }
    __syncthreads();
#pragma unroll
    for (int p = 0; p < 2; ++p) {
        int n = p * 32 + (threadIdx.x >> 3);
        int k8 = threadIdx.x & 7;
        int slot = k8 ^ ((n & 7) ^ ((n >> 3) & 7));
        u16x8 v = *(u16x8*)((char*)t + n * 128 + slot * 16);
        *(u16x8*)&dst[mat + (size_t)(n0 + n) * K + k0 + k8 * 8] = v;
    }
}

// ============ router: logits (fp64 accum), argmax, max softmax prob; fused bf16 cvt ============
__global__ __launch_bounds__(256) void router_kernel(const float* __restrict__ hidden,
                                                     const float* __restrict__ gate_w,
                                                     float* __restrict__ logits_out,
                                                     int* __restrict__ sel,
                                                     float* __restrict__ maxp,
                                                     u16* __restrict__ xbf) {
    __shared__ float gw[D_ * E_];   // 32 KB
    for (int i = threadIdx.x; i < D_ * E_ / 4; i += 256)
        ((float4*)gw)[i] = ((const float4*)gate_w)[i];
    __syncthreads();

    int wave = threadIdx.x >> 6, lane = threadIdx.x & 63;
    int tok = blockIdx.x * 4 + wave;              // [0, B*S)
    const float* hrow = hidden + (size_t)tok * D_;
    u16* xrow = xbf + (size_t)tok * D_;

    double acc[8] = {0, 0, 0, 0, 0, 0, 0, 0};
#pragma unroll 4
    for (int i = 0; i < D_ / 64; i++) {
        int d = i * 64 + lane;
        float h = hrow[d];
        xrow[d] = f2bf(h);
        const float4* g4 = (const float4*)(gw + d * 8);
        float4 g0 = g4[0], g1 = g4[1];
        acc[0] += (double)h * g0.x; acc[1] += (double)h * g0.y;
        acc[2] += (double)h * g0.z; acc[3] += (double)h * g0.w;
        acc[4] += (double)h * g1.x; acc[5] += (double)h * g1.y;
        acc[6] += (double)h * g1.z; acc[7] += (double)h * g1.w;
    }
#pragma unroll
    for (int off = 32; off > 0; off >>= 1)
#pragma unroll
        for (int e = 0; e < 8; e++)
            acc[e] += __shfl_xor(acc[e], off);

    float l[8];
#pragma unroll
    for (int e = 0; e < 8; e++) l[e] = (float)acc[e];
    if (lane < 8) logits_out[(size_t)tok * 8 + lane] = l[lane];

    int am = 0; float mx = l[0];
#pragma unroll
    for (int e = 1; e < 8; e++) if (l[e] > mx) { mx = l[e]; am = e; }
    float sum = 0.f;
#pragma unroll
    for (int e = 0; e < 8; e++) sum += expf(l[e] - mx);
    if (lane == 0) { sel[tok] = am; maxp[tok] = 1.0f / sum; }
}

// ============ routing scan: hierarchical (histogram -> prefix -> assign), 1 block/batch ============
__global__ __launch_bounds__(1024) void scan_kernel(const int* __restrict__ sel,
                                                    int* __restrict__ pos,
                                                    int* __restrict__ slot_token,
                                                    int* __restrict__ counts) {
    __shared__ int hist[16][8];
    __shared__ int base[16][8];
    int b = blockIdx.x;
    int tid = threadIdx.x, wv = tid >> 6, l = tid & 63;
    unsigned long long below = (l == 0) ? 0ull : ((~0ull) >> (64 - l));
    const int* sb = sel + b * S_;

    int eloc[4];
    int cnt[8] = {0, 0, 0, 0, 0, 0, 0, 0};
#pragma unroll
    for (int c = 0; c < 4; c++) {
        int s = wv * 256 + c * 64 + l;
        int e = sb[s];
        eloc[c] = e;
#pragma unroll
        for (int ex = 0; ex < 8; ex++)
            cnt[ex] += (int)__popcll(__ballot(e == ex));
    }
    if (l == 0)
#pragma unroll
        for (int ex = 0; ex < 8; ex++) hist[wv][ex] = cnt[ex];
    __syncthreads();
    if (tid < 128) {
        int ex = tid & 7, v = tid >> 3;
        int s = 0;
        for (int w2 = 0; w2 < v; w2++) s += hist[w2][ex];
        base[v][ex] = s;
        if (v == 15) {
            int tot = s + hist[15][ex];
            counts[b * 8 + ex] = tot < C_ ? tot : C_;
        }
    }
    __syncthreads();
    int carry[8];
#pragma unroll
    for (int ex = 0; ex < 8; ex++) carry[ex] = base[wv][ex];
#pragma unroll
    for (int c = 0; c < 4; c++) {
        int s = wv * 256 + c * 64 + l;
        int e = eloc[c];
        int p = 0;
#pragma unroll
        for (int ex = 0; ex < 8; ex++) {
            unsigned long long m = __ballot(e == ex);
            if (e == ex) p = carry[ex] + (int)__popcll(m & below);
            carry[ex] += (int)__popcll(m);
        }
        pos[b * S_ + s] = p;
        if (p < C_) slot_token[(b * E_ + e) * C_ + p] = s;
    }
}

// ============ GEMM1: h = silu(x@w1) * (x@w3) ============
// m97-style: tile 128(slots) x 128(ff), dual panel, BK=64 as 2x[128][32] sub-tiles,
// single-buffer LDS 48 KB, 4 waves (2x2), wave 64x64, simple 2-barrier loop.
// Chunk swizzle (R4, measured 0 conflicts): 64B sub-rows, phys chunk = c ^ ((r>>1)&3);
// global_load_lds dest linear, source inverse-permuted, read applies same XOR.
__global__ __launch_bounds__(256) void gemm1_kernel(const u16* __restrict__ x,
                                                    const u16* __restrict__ w1t,
                                                    const u16* __restrict__ w3t,
                                                    const int* __restrict__ slot_token,
                                                    const int* __restrict__ counts,
                                                    u16* __restrict__ hbuf) {
    __shared__ u16 As[8192], B1s[8192], B3s[8192];   // 48 KB
    // bijective XCD chunk swizzle (nwg = 4096, q = 512)
    int phys = blockIdx.x + 32 * (blockIdx.y + 8 * blockIdx.z);
    int virt = (phys & 7) * 512 + (phys >> 3);
    int bx = virt & 31, by = (virt >> 5) & 7, bz = virt >> 8;

    int z = bz;
    int cnt = counts[z];
    int c0 = by * 128;
    if (c0 >= cnt) return;
    int n0 = bx * 128;
    int b = z >> 3, e = z & 7;

    int tid = threadIdx.x, w = tid >> 6, l = tid & 63;
    int wm = w >> 1, wn = w & 1;

    // staging sources: load i covers q = i*256+tid of 1024 16B-chunks per tile
    const u16 *sA[4], *sB1[4], *sB3[4];
#pragma unroll
    for (int i = 0; i < 4; i++) {
        int q = i * 256 + tid;
        int kkr = q >> 9, r = (q >> 2) & 127, c = q & 3;
        int lc = c ^ ((r >> 1) & 3);
        int ko = kkr * 32 + lc * 8;
        int slot = c0 + r;
        int tok = (slot < cnt) ? slot_token[z * C_ + slot] : 0;
        sA[i]  = x + (size_t)(b * S_ + tok) * D_ + ko;
        sB1[i] = w1t + ((size_t)e * FF_ + n0 + r) * D_ + ko;
        sB3[i] = w3t + ((size_t)e * FF_ + n0 + r) * D_ + ko;
    }
    u32 dst0 = (u32)w * 512;   // + i*2048 (u16 units); lane adds 8 u16 implicitly

    // fragment read offsets (u16): sub-tile kk*4096 + row*32 + ((l>>4)^((l>>1)&3))*8
    u32 ck = (u32)(((l >> 4) ^ ((l >> 1) & 3)) * 8);
    u32 ao[4], bo[4];
#pragma unroll
    for (int f = 0; f < 4; f++) {
        ao[f] = (u32)(wm * 64 + f * 16 + (l & 15)) * 32 + ck;
        bo[f] = (u32)(wn * 64 + f * 16 + (l & 15)) * 32 + ck;
    }

    f32x4 acc1[4][4] = {};
    f32x4 acc3[4][4] = {};

    for (int t = 0; t < D_ / 64; ++t) {
        int k0 = t * 64;
        if (t) __syncthreads();
#pragma unroll
        for (int i = 0; i < 4; i++) {
            gload_lds16(sA[i]  + k0, As  + i * 2048 + dst0);
            gload_lds16(sB1[i] + k0, B1s + i * 2048 + dst0);
            gload_lds16(sB3[i] + k0, B3s + i * 2048 + dst0);
        }
        __syncthreads();   // compiler drains vmcnt(0) here: staged data visible
#pragma unroll
        for (int kk = 0; kk < 2; kk++) {
            u32 kb = (u32)kk * 4096;
            bf16x8 af[4], b1f[4], b3f[4];
#pragma unroll
            for (int f = 0; f < 4; f++) af[f]  = *(const bf16x8*)(As  + kb + ao[f]);
#pragma unroll
            for (int f = 0; f < 4; f++) b1f[f] = *(const bf16x8*)(B1s + kb + bo[f]);
#pragma unroll
            for (int f = 0; f < 4; f++) b3f[f] = *(const bf16x8*)(B3s + kb + bo[f]);
#pragma unroll
            for (int fm = 0; fm < 4; fm++)
#pragma unroll
                for (int fn = 0; fn < 4; fn++) {
                    acc1[fm][fn] = __builtin_amdgcn_mfma_f32_16x16x32_bf16(af[fm], b1f[fn], acc1[fm][fn], 0, 0, 0);
                    acc3[fm][fn] = __builtin_amdgcn_mfma_f32_16x16x32_bf16(af[fm], b3f[fn], acc3[fm][fn], 0, 0, 0);
                }
        }
    }

#pragma unroll
    for (int fm = 0; fm < 4; fm++) {
        int rb = c0 + wm * 64 + fm * 16 + ((l >> 4) << 2);
#pragma unroll
        for (int fn = 0; fn < 4; fn++) {
            int col = n0 + wn * 64 + fn * 16 + (l & 15);
#pragma unroll
            for (int r = 0; r < 4; r++) {
                int slot = rb + r;
                if (slot < cnt) {
                    float g = acc1[fm][fn][r], uu = acc3[fm][fn][r];
                    float h = (g / (1.f + __expf(-g))) * uu;
                    hbuf[((size_t)z * C_ + slot) * FF_ + col] = f2bf(h);
                }
            }
        }
    }
}

// ============ GEMM2: out[token] = maxp * (h @ w2), scatter epilogue ============
// m97-style: tile 128(slots) x 128(d), BK=64, single-buffer 32 KB, 4 waves, wave 64x64.
__global__ __launch_bounds__(256) void gemm2_kernel(const u16* __restrict__ hbuf,
                                                    const u16* __restrict__ w2t,
                                                    const int* __restrict__ slot_token,
                                                    const int* __restrict__ counts,
                                                    const float* __restrict__ maxp,
                                                    float* __restrict__ out) {
    __shared__ u16 As[8192], Bs[8192];   // 32 KB
    // bijective XCD chunk swizzle (nwg = 1024, q = 128)
    int phys = blockIdx.x + 8 * (blockIdx.y + 8 * blockIdx.z);
    int virt = (phys & 7) * 128 + (phys >> 3);
    int bx = virt & 7, by = (virt >> 3) & 7, bz = virt >> 6;

    int z = bz;
    int cnt = counts[z];
    int c0 = by * 128;
    if (c0 >= cnt) return;
    int n0 = bx * 128;
    int b = z >> 3, e = z & 7;

    int tid = threadIdx.x, w = tid >> 6, l = tid & 63;
    int wm = w >> 1, wn = w & 1;

    const u16 *sA[4], *sB[4];
#pragma unroll
    for (int i = 0; i < 4; i++) {
        int q = i * 256 + tid;
        int kkr = q >> 9, r = (q >> 2) & 127, c = q & 3;
        int lc = c ^ ((r >> 1) & 3);
        int ko = kkr * 32 + lc * 8;
        sA[i] = hbuf + ((size_t)z * C_ + c0 + r) * FF_ + ko;
        sB[i] = w2t + ((size_t)e * D_ + n0 + r) * FF_ + ko;
    }
    u32 dst0 = (u32)w * 512;

    u32 ck = (u32)(((l >> 4) ^ ((l >> 1) & 3)) * 8);
    u32 ao[4], bo[4];
#pragma unroll
    for (int f = 0; f < 4; f++) {
        ao[f] = (u32)(wm * 64 + f * 16 + (l & 15)) * 32 + ck;
        bo[f] = (u32)(wn * 64 + f * 16 + (l & 15)) * 32 + ck;
    }

    f32x4 acc[4][4] = {};

    for (int t = 0; t < FF_ / 64; ++t) {
        int k0 = t * 64;
        if (t) __syncthreads();
#pragma unroll
        for (int i = 0; i < 4; i++) {
            gload_lds16(sA[i] + k0, As + i * 2048 + dst0);
            gload_lds16(sB[i] + k0, Bs + i * 2048 + dst0);
        }
        __syncthreads();
#pragma unroll
        for (int kk = 0; kk < 2; kk++) {
            u32 kb = (u32)kk * 4096;
            bf16x8 af[4], bfv[4];
#pragma unroll
            for (int f = 0; f < 4; f++) af[f]  = *(const bf16x8*)(As + kb + ao[f]);
#pragma unroll
            for (int f = 0; f < 4; f++) bfv[f] = *(const bf16x8*)(Bs + kb + bo[f]);
#pragma unroll
            for (int fm = 0; fm < 4; fm++)
#pragma unroll
                for (int fn = 0; fn < 4; fn++)
                    acc[fm][fn] = __builtin_amdgcn_mfma_f32_16x16x32_bf16(af[fm], bfv[fn], acc[fm][fn], 0, 0, 0);
        }
    }

#pragma unroll
    for (int fm = 0; fm < 4; fm++) {
        int rb = c0 + wm * 64 + fm * 16 + ((l >> 4) << 2);
#pragma unroll
        for (int r = 0; r < 4; r++) {
            int slot = rb + r;
            if (slot < cnt) {
                int s = slot_token[z * C_ + slot];
                float sc = maxp[b * S_ + s];
                float* orow = out + ((size_t)b * S_ + s) * D_ + n0 + wn * 64 + (l & 15);
#pragma unroll
                for (int fn = 0; fn < 4; fn++)
                    orow[fn * 16] = sc * acc[fm][fn][r];
            }
        }
    }
}

// ============ dropped tokens keep hidden (rare; usually no-op) ============
__global__ __launch_bounds__(256) void combine_dropped(const float* __restrict__ hidden,
                                                       const int* __restrict__ pos,
                                                       const float* __restrict__ maxp,
                                                       float* __restrict__ out) {
    int t = blockIdx.x;
    if (pos[t] < C_) return;
    float sc = maxp[t];
    const float* src = hidden + (size_t)t * D_;
    float* dst = out + (size_t)t * D_;
    for (int d = threadIdx.x; d < D_; d += 256) dst[d] = sc * src[d];
}

extern "C" void kernel_launch(void* const* d_in, const int* in_sizes, int n_in,
                              void* d_out, int out_size, void* d_ws, size_t ws_size,
                              hipStream_t stream) {
    const float* hidden = (const float*)d_in[0];
    const float* gate_w = (const float*)d_in[1];
    const float* w1     = (const float*)d_in[2];
    const float* w2     = (const float*)d_in[3];
    const float* w3     = (const float*)d_in[4];

    float* out        = (float*)d_out;
    float* logits_out = out + (size_t)B_ * S_ * D_;

    char* ws = (char*)d_ws;
    u16* hidden_bf = (u16*)ws;            ws += (size_t)B_ * S_ * D_ * 2;
    u16* w1t       = (u16*)ws;            ws += (size_t)E_ * D_ * FF_ * 2;
    u16* w3t       = (u16*)ws;            ws += (size_t)E_ * D_ * FF_ * 2;
    u16* w2t       = (u16*)ws;            ws += (size_t)E_ * D_ * FF_ * 2;
    u16* hbuf      = (u16*)ws;            ws += (size_t)B_ * E_ * C_ * FF_ * 2;
    int*   sel        = (int*)ws;         ws += (size_t)B_ * S_ * 4;
    int*   pos        = (int*)ws;         ws += (size_t)B_ * S_ * 4;
    float* maxp       = (float*)ws;       ws += (size_t)B_ * S_ * 4;
    int*   slot_token = (int*)ws;         ws += (size_t)B_ * E_ * C_ * 4;
    int*   counts     = (int*)ws;         ws += (size_t)B_ * E_ * 4;

    router_kernel<<<B_ * S_ / 4, 256, 0, stream>>>(hidden, gate_w, logits_out, sel, maxp, hidden_bf);
    scan_kernel<<<B_, 1024, 0, stream>>>(sel, pos, slot_token, counts);

    transpose_cvt<<<dim3(FF_ / 64, D_ / 64, E_), 256, 0, stream>>>(w1, w1t, D_, FF_);
    transpose_cvt<<<dim3(FF_ / 64, D_ / 64, E_), 256, 0, stream>>>(w3, w3t, D_, FF_);
    transpose_cvt<<<dim3(D_ / 64, FF_ / 64, E_), 256, 0, stream>>>(w2, w2t, FF_, D_);

    gemm1_kernel<<<dim3(32, 8, 16), 256, 0, stream>>>(hidden_bf, w1t, w3t, slot_token, counts, hbuf);
    gemm2_kernel<<<dim3(8, 8, 16), 256, 0, stream>>>(hbuf, w2t, slot_token, counts, maxp, out);
    combine_dropped<<<B_ * S_, 256, 0, stream>>>(hidden, pos, maxp, out);
}

// Round 7
// 535.739 us; speedup vs baseline: 1.1875x; 1.1875x over previous
//
#include <hip/hip_runtime.h>
#include <hip/hip_bf16.h>
#include <stdint.h>

#define B_  2
#define S_  4096
#define D_  1024
#define FF_ 4096
#define E_  8
#define C_  1024

typedef unsigned short u16;
typedef unsigned int   u32;
typedef float f32x4  __attribute__((ext_vector_type(4)));
typedef short bf16x8 __attribute__((ext_vector_type(8)));
typedef u16   u16x8  __attribute__((ext_vector_type(8)));

static __device__ __forceinline__ u16 f2bf(float f) {
    union { float f; u32 u; } v; v.f = f;
    u32 u = v.u;
    u32 r = (u + 0x7FFFu + ((u >> 16) & 1u)) >> 16;  // RNE; inputs are finite
    return (u16)r;
}

#define LGKM0() asm volatile("s_waitcnt lgkmcnt(0)" ::: "memory")
#define BAR()   asm volatile("s_barrier" ::: "memory")

// ============ transpose + convert: [K][N] fp32 -> [N][K] bf16, per expert ============
__global__ __launch_bounds__(256) void transpose_cvt(const float* __restrict__ src,
                                                     u16* __restrict__ dst, int K, int N) {
    __shared__ u16 t[64 * 64];
    size_t mat = (size_t)blockIdx.z * K * N;
    int n0 = blockIdx.x * 64, k0 = blockIdx.y * 64;
    int l = threadIdx.x & 63, w = threadIdx.x >> 6;
#pragma unroll
    for (int p = 0; p < 2; ++p) {
        int k = p * 32 + w * 8 + ((l >> 4) << 1);     // even k
        int n = (l & 15) * 4;
        float4 v0 = *(const float4*)&src[mat + (size_t)(k0 + k) * N + n0 + n];
        float4 v1 = *(const float4*)&src[mat + (size_t)(k0 + k + 1) * N + n0 + n];
        float a0[4] = {v0.x, v0.y, v0.z, v0.w};
        float a1[4] = {v1.x, v1.y, v1.z, v1.w};
#pragma unroll
        for (int j = 0; j < 4; ++j) {
            int nn = n + j;
            u32 pk = (u32)f2bf(a0[j]) | ((u32)f2bf(a1[j]) << 16);
            int slot = (k >> 3) ^ ((nn & 7) ^ ((nn >> 3) & 7));
            *(u32*)((char*)t + nn * 128 + slot * 16 + (k & 7) * 2) = pk;
        }
    }
    __syncthreads();
#pragma unroll
    for (int p = 0; p < 2; ++p) {
        int n = p * 32 + (threadIdx.x >> 3);
        int k8 = threadIdx.x & 7;
        int slot = k8 ^ ((n & 7) ^ ((n >> 3) & 7));
        u16x8 v = *(u16x8*)((char*)t + n * 128 + slot * 16);
        *(u16x8*)&dst[mat + (size_t)(n0 + n) * K + k0 + k8 * 8] = v;
    }
}

// ============ router: logits (fp64 accum), argmax, max softmax prob; fused bf16 cvt ============
__global__ __launch_bounds__(256) void router_kernel(const float* __restrict__ hidden,
                                                     const float* __restrict__ gate_w,
                                                     float* __restrict__ logits_out,
                                                     int* __restrict__ sel,
                                                     float* __restrict__ maxp,
                                                     u16* __restrict__ xbf) {
    __shared__ float gw[D_ * E_];   // 32 KB
    for (int i = threadIdx.x; i < D_ * E_ / 4; i += 256)
        ((float4*)gw)[i] = ((const float4*)gate_w)[i];
    __syncthreads();

    int wave = threadIdx.x >> 6, lane = threadIdx.x & 63;
    int tok = blockIdx.x * 4 + wave;              // [0, B*S)
    const float* hrow = hidden + (size_t)tok * D_;
    u16* xrow = xbf + (size_t)tok * D_;

    double acc[8] = {0, 0, 0, 0, 0, 0, 0, 0};
#pragma unroll 4
    for (int i = 0; i < D_ / 64; i++) {
        int d = i * 64 + lane;
        float h = hrow[d];
        xrow[d] = f2bf(h);
        const float4* g4 = (const float4*)(gw + d * 8);
        float4 g0 = g4[0], g1 = g4[1];
        acc[0] += (double)h * g0.x; acc[1] += (double)h * g0.y;
        acc[2] += (double)h * g0.z; acc[3] += (double)h * g0.w;
        acc[4] += (double)h * g1.x; acc[5] += (double)h * g1.y;
        acc[6] += (double)h * g1.z; acc[7] += (double)h * g1.w;
    }
#pragma unroll
    for (int off = 32; off > 0; off >>= 1)
#pragma unroll
        for (int e = 0; e < 8; e++)
            acc[e] += __shfl_xor(acc[e], off);

    float l[8];
#pragma unroll
    for (int e = 0; e < 8; e++) l[e] = (float)acc[e];
    if (lane < 8) logits_out[(size_t)tok * 8 + lane] = l[lane];

    int am = 0; float mx = l[0];
#pragma unroll
    for (int e = 1; e < 8; e++) if (l[e] > mx) { mx = l[e]; am = e; }
    float sum = 0.f;
#pragma unroll
    for (int e = 0; e < 8; e++) sum += expf(l[e] - mx);
    if (lane == 0) { sel[tok] = am; maxp[tok] = 1.0f / sum; }
}

// ============ routing scan: hierarchical (histogram -> prefix -> assign), 1 block/batch ============
__global__ __launch_bounds__(1024) void scan_kernel(const int* __restrict__ sel,
                                                    int* __restrict__ pos,
                                                    int* __restrict__ slot_token,
                                                    int* __restrict__ counts) {
    __shared__ int hist[16][8];
    __shared__ int base[16][8];
    int b = blockIdx.x;
    int tid = threadIdx.x, wv = tid >> 6, l = tid & 63;
    unsigned long long below = (l == 0) ? 0ull : ((~0ull) >> (64 - l));
    const int* sb = sel + b * S_;

    int eloc[4];
    int cnt[8] = {0, 0, 0, 0, 0, 0, 0, 0};
#pragma unroll
    for (int c = 0; c < 4; c++) {
        int s = wv * 256 + c * 64 + l;
        int e = sb[s];
        eloc[c] = e;
#pragma unroll
        for (int ex = 0; ex < 8; ex++)
            cnt[ex] += (int)__popcll(__ballot(e == ex));
    }
    if (l == 0)
#pragma unroll
        for (int ex = 0; ex < 8; ex++) hist[wv][ex] = cnt[ex];
    __syncthreads();
    if (tid < 128) {
        int ex = tid & 7, v = tid >> 3;
        int s = 0;
        for (int w2 = 0; w2 < v; w2++) s += hist[w2][ex];
        base[v][ex] = s;
        if (v == 15) {
            int tot = s + hist[15][ex];
            counts[b * 8 + ex] = tot < C_ ? tot : C_;
        }
    }
    __syncthreads();
    int carry[8];
#pragma unroll
    for (int ex = 0; ex < 8; ex++) carry[ex] = base[wv][ex];
#pragma unroll
    for (int c = 0; c < 4; c++) {
        int s = wv * 256 + c * 64 + l;
        int e = eloc[c];
        int p = 0;
#pragma unroll
        for (int ex = 0; ex < 8; ex++) {
            unsigned long long m = __ballot(e == ex);
            if (e == ex) p = carry[ex] + (int)__popcll(m & below);
            carry[ex] += (int)__popcll(m);
        }
        pos[b * S_ + s] = p;
        if (p < C_) slot_token[(b * E_ + e) * C_ + p] = s;
    }
}

// ============ GEMM1: h = silu(x@w1) * (x@w3) ============
// M256 x ff128-dual, BK=32, NK=32. Reg-staged (T14): 2 named stage-sets/thread (64B each),
// 2 LDS slots (32 KB each), 1 barrier/iter. Chunk-XOR LDS layout (verified 0-conflict):
// phys16B-chunk = logical ^ ((row>>1)&3); write side applies source-XOR, read side ck-XOR.
__global__ __launch_bounds__(512, 2) void gemm1_kernel(const u16* __restrict__ x,
                                                       const u16* __restrict__ w1t,
                                                       const u16* __restrict__ w3t,
                                                       const int* __restrict__ slot_token,
                                                       const int* __restrict__ counts,
                                                       u16* __restrict__ hbuf) {
    extern __shared__ u16 lds[];   // 2 * 16384 u16 = 64 KB
    // bijective XCD chunk swizzle (nwg = 2048, q = 256)
    int phys = blockIdx.x + 32 * (blockIdx.y + 4 * blockIdx.z);
    int virt = (phys & 7) * 256 + (phys >> 3);
    int bx = virt & 31, by = (virt >> 5) & 3, bz = virt >> 7;

    int z = bz;
    int cnt = counts[z];
    int c0 = by * 256;
    if (c0 >= cnt) return;
    int n0 = bx * 128;
    int b = z >> 3, e = z & 7;

    int tid = threadIdx.x, w = tid >> 6, l = tid & 63;
    int wm = w >> 2, wn = w & 3;

    // staging: thread covers 16B chunk (r=tid>>2, c=tid&3) of A rows r & r+128, B1 row r, B3 row r
    int r = tid >> 2;
    int lc = ((tid & 3) ^ ((tid >> 3) & 3)) * 8;   // source k-offset (inverse chunk swizzle)
    int sl0 = c0 + r, sl1 = c0 + 128 + r;
    int tok0 = slot_token[z * C_ + (sl0 < cnt ? sl0 : 0)];
    int tok1 = slot_token[z * C_ + (sl1 < cnt ? sl1 : 0)];
    const u16* pA0 = x + (size_t)(b * S_ + tok0) * D_ + lc;
    const u16* pA1 = x + (size_t)(b * S_ + tok1) * D_ + lc;
    const u16* pB1 = w1t + ((size_t)e * FF_ + n0 + r) * D_ + lc;
    const u16* pB3 = w3t + ((size_t)e * FF_ + n0 + r) * D_ + lc;
    u32 wA0 = (u32)tid * 8, wA1 = (u32)tid * 8 + 4096;
    u32 wB1 = 8192 + (u32)tid * 8, wB3 = 12288 + (u32)tid * 8;

    u32 ck  = (u32)(((l >> 4) ^ ((l >> 1) & 3)) * 8);
    u32 ao  = (u32)(wm * 128 + (l & 15)) * 32 + ck;           // + f*512
    u32 b1o = 8192  + (u32)(wn * 32 + (l & 15)) * 32 + ck;    // + n*512
    u32 b3o = 12288 + (u32)(wn * 32 + (l & 15)) * 32 + ck;

    f32x4 acc1[8][2] = {};
    f32x4 acc3[8][2] = {};

    u16x8 s0A0, s0A1, s0B1, s0B3, s1A0, s1A1, s1B1, s1B3;

#define G1LOAD(SA0, SA1, SB1, SB3, T) do { \
        int _kl = ((T) < 32 ? (T) : 31) << 5; \
        SA0 = *(const u16x8*)(pA0 + _kl); SA1 = *(const u16x8*)(pA1 + _kl); \
        SB1 = *(const u16x8*)(pB1 + _kl); SB3 = *(const u16x8*)(pB3 + _kl); } while (0)

#define G1ITER(T, RD, WR, SA0, SA1, SB1, SB3) do { \
        LGKM0(); BAR(); \
        const u16* Ls = lds + (RD); u16* Ld = lds + (WR); \
        bf16x8 af[8], b1f[2], b3f[2]; \
        _Pragma("unroll") for (int f = 0; f < 8; f++) af[f] = *(const bf16x8*)(Ls + ao + f * 512); \
        _Pragma("unroll") for (int n = 0; n < 2; n++) { \
            b1f[n] = *(const bf16x8*)(Ls + b1o + n * 512); \
            b3f[n] = *(const bf16x8*)(Ls + b3o + n * 512); } \
        *(u16x8*)(Ld + wA0) = SA0; *(u16x8*)(Ld + wA1) = SA1; \
        *(u16x8*)(Ld + wB1) = SB1; *(u16x8*)(Ld + wB3) = SB3; \
        G1LOAD(SA0, SA1, SB1, SB3, (T) + 3); \
        __builtin_amdgcn_s_setprio(1); \
        _Pragma("unroll") for (int f = 0; f < 8; f++) \
            _Pragma("unroll") for (int n = 0; n < 2; n++) { \
                acc1[f][n] = __builtin_amdgcn_mfma_f32_16x16x32_bf16(af[f], b1f[n], acc1[f][n], 0, 0, 0); \
                acc3[f][n] = __builtin_amdgcn_mfma_f32_16x16x32_bf16(af[f], b3f[n], acc3[f][n], 0, 0, 0); } \
        __builtin_amdgcn_s_setprio(0); } while (0)

    // prologue: tile0 -> slot0 via regs; tiles 1,2 into stage sets
    G1LOAD(s0A0, s0A1, s0B1, s0B3, 0);
    *(u16x8*)(lds + wA0) = s0A0; *(u16x8*)(lds + wA1) = s0A1;
    *(u16x8*)(lds + wB1) = s0B1; *(u16x8*)(lds + wB3) = s0B3;
    G1LOAD(s0A0, s0A1, s0B1, s0B3, 1);
    G1LOAD(s1A0, s1A1, s1B1, s1B3, 2);

    for (int t = 0; t < 32; t += 2) {
        G1ITER(t,     0, 16384, s0A0, s0A1, s0B1, s0B3);
        G1ITER(t + 1, 16384, 0, s1A0, s1A1, s1B1, s1B3);
    }

#pragma unroll
    for (int f = 0; f < 8; f++) {
        int row = wm * 128 + f * 16 + ((l >> 4) << 2);
#pragma unroll
        for (int rr = 0; rr < 4; rr++) {
            int slot = c0 + row + rr;
            if (slot < cnt) {
                size_t base = ((size_t)z * C_ + slot) * FF_ + n0 + wn * 32 + (l & 15);
#pragma unroll
                for (int n = 0; n < 2; n++) {
                    float g = acc1[f][n][rr], uu = acc3[f][n][rr];
                    float h = (g / (1.f + __expf(-g))) * uu;
                    hbuf[base + n * 16] = f2bf(h);
                }
            }
        }
    }
#undef G1LOAD
#undef G1ITER
}

// ============ GEMM2: out[token] = maxp * (h @ w2), scatter epilogue ============
// M128 x N256, BK=32, NK=128, reg-staged, 2 LDS slots (24 KB each), 1 barrier/iter.
__global__ __launch_bounds__(512, 2) void gemm2_kernel(const u16* __restrict__ hbuf,
                                                       const u16* __restrict__ w2t,
                                                       const int* __restrict__ slot_token,
                                                       const int* __restrict__ counts,
                                                       const float* __restrict__ maxp,
                                                       float* __restrict__ out) {
    extern __shared__ u16 lds[];   // 2 * 12288 u16 = 48 KB
    // bijective XCD chunk swizzle (nwg = 512, q = 64)
    int phys = blockIdx.x + 4 * (blockIdx.y + 8 * blockIdx.z);
    int virt = (phys & 7) * 64 + (phys >> 3);
    int bx = virt & 3, by = (virt >> 2) & 7, bz = virt >> 5;

    int z = bz;
    int cnt = counts[z];
    int c0 = by * 128;
    if (c0 >= cnt) return;
    int n0 = bx * 256;
    int b = z >> 3, e = z & 7;

    int tid = threadIdx.x, w = tid >> 6, l = tid & 63;
    int wm = w >> 2, wn = w & 3;

    int r = tid >> 2;
    int lc = ((tid & 3) ^ ((tid >> 3) & 3)) * 8;
    const u16* pA  = hbuf + ((size_t)z * C_ + c0 + r) * FF_ + lc;
    const u16* pB0 = w2t + ((size_t)e * D_ + n0 + r) * FF_ + lc;
    const u16* pB1 = w2t + ((size_t)e * D_ + n0 + 128 + r) * FF_ + lc;
    u32 wA = (u32)tid * 8, wB0 = 4096 + (u32)tid * 8, wB1w = 8192 + (u32)tid * 8;

    u32 ck = (u32)(((l >> 4) ^ ((l >> 1) & 3)) * 8);
    u32 ao = (u32)(wm * 64 + (l & 15)) * 32 + ck;           // + f*512
    u32 bo = 4096 + (u32)(wn * 64 + (l & 15)) * 32 + ck;    // + n*512

    f32x4 acc[4][4] = {};

    u16x8 s0A, s0B0, s0B1, s1A, s1B0, s1B1;

#define G2LOAD(SA, SB0, SB1, T) do { \
        int _kl = ((T) < 128 ? (T) : 127) << 5; \
        SA  = *(const u16x8*)(pA  + _kl); \
        SB0 = *(const u16x8*)(pB0 + _kl); SB1 = *(const u16x8*)(pB1 + _kl); } while (0)

#define G2ITER(T, RD, WR, SA, SB0, SB1) do { \
        LGKM0(); BAR(); \
        const u16* Ls = lds + (RD); u16* Ld = lds + (WR); \
        bf16x8 af[4], bfv[4]; \
        _Pragma("unroll") for (int f = 0; f < 4; f++) af[f]  = *(const bf16x8*)(Ls + ao + f * 512); \
        _Pragma("unroll") for (int n = 0; n < 4; n++) bfv[n] = *(const bf16x8*)(Ls + bo + n * 512); \
        *(u16x8*)(Ld + wA) = SA; *(u16x8*)(Ld + wB0) = SB0; *(u16x8*)(Ld + wB1w) = SB1; \
        G2LOAD(SA, SB0, SB1, (T) + 3); \
        __builtin_amdgcn_s_setprio(1); \
        _Pragma("unroll") for (int f = 0; f < 4; f++) \
            _Pragma("unroll") for (int n = 0; n < 4; n++) \
                acc[f][n] = __builtin_amdgcn_mfma_f32_16x16x32_bf16(af[f], bfv[n], acc[f][n], 0, 0, 0); \
        __builtin_amdgcn_s_setprio(0); } while (0)

    G2LOAD(s0A, s0B0, s0B1, 0);
    *(u16x8*)(lds + wA) = s0A; *(u16x8*)(lds + wB0) = s0B0; *(u16x8*)(lds + wB1w) = s0B1;
    G2LOAD(s0A, s0B0, s0B1, 1);
    G2LOAD(s1A, s1B0, s1B1, 2);

    for (int t = 0; t < 128; t += 2) {
        G2ITER(t,     0, 12288, s0A, s0B0, s0B1);
        G2ITER(t + 1, 12288, 0, s1A, s1B0, s1B1);
    }

#pragma unroll
    for (int f = 0; f < 4; f++) {
        int row = wm * 64 + f * 16 + ((l >> 4) << 2);
#pragma unroll
        for (int rr = 0; rr < 4; rr++) {
            int slot = c0 + row + rr;
            if (slot < cnt) {
                int s = slot_token[z * C_ + slot];
                float sc = maxp[b * S_ + s];
                float* orow = out + ((size_t)b * S_ + s) * D_ + n0 + wn * 64 + (l & 15);
#pragma unroll
                for (int n = 0; n < 4; n++)
                    orow[n * 16] = sc * acc[f][n][rr];
            }
        }
    }
#undef G2LOAD
#undef G2ITER
}

// ============ dropped tokens keep hidden (rare; usually no-op) ============
__global__ __launch_bounds__(256) void combine_dropped(const float* __restrict__ hidden,
                                                       const int* __restrict__ pos,
                                                       const float* __restrict__ maxp,
                                                       float* __restrict__ out) {
    int t = blockIdx.x;
    if (pos[t] < C_) return;
    float sc = maxp[t];
    const float* src = hidden + (size_t)t * D_;
    float* dst = out + (size_t)t * D_;
    for (int d = threadIdx.x; d < D_; d += 256) dst[d] = sc * src[d];
}

extern "C" void kernel_launch(void* const* d_in, const int* in_sizes, int n_in,
                              void* d_out, int out_size, void* d_ws, size_t ws_size,
                              hipStream_t stream) {
    const float* hidden = (const float*)d_in[0];
    const float* gate_w = (const float*)d_in[1];
    const float* w1     = (const float*)d_in[2];
    const float* w2     = (const float*)d_in[3];
    const float* w3     = (const float*)d_in[4];

    float* out        = (float*)d_out;
    float* logits_out = out + (size_t)B_ * S_ * D_;

    char* ws = (char*)d_ws;
    u16* hidden_bf = (u16*)ws;            ws += (size_t)B_ * S_ * D_ * 2;
    u16* w1t       = (u16*)ws;            ws += (size_t)E_ * D_ * FF_ * 2;
    u16* w3t       = (u16*)ws;            ws += (size_t)E_ * D_ * FF_ * 2;
    u16* w2t       = (u16*)ws;            ws += (size_t)E_ * D_ * FF_ * 2;
    u16* hbuf      = (u16*)ws;            ws += (size_t)B_ * E_ * C_ * FF_ * 2;
    int*   sel        = (int*)ws;         ws += (size_t)B_ * S_ * 4;
    int*   pos        = (int*)ws;         ws += (size_t)B_ * S_ * 4;
    float* maxp       = (float*)ws;       ws += (size_t)B_ * S_ * 4;
    int*   slot_token = (int*)ws;         ws += (size_t)B_ * E_ * C_ * 4;
    int*   counts     = (int*)ws;         ws += (size_t)B_ * E_ * 4;

    (void)hipFuncSetAttribute((const void*)gemm1_kernel,
                              hipFuncAttributeMaxDynamicSharedMemorySize, 65536);
    (void)hipFuncSetAttribute((const void*)gemm2_kernel,
                              hipFuncAttributeMaxDynamicSharedMemorySize, 49152);

    router_kernel<<<B_ * S_ / 4, 256, 0, stream>>>(hidden, gate_w, logits_out, sel, maxp, hidden_bf);
    scan_kernel<<<B_, 1024, 0, stream>>>(sel, pos, slot_token, counts);

    transpose_cvt<<<dim3(FF_ / 64, D_ / 64, E_), 256, 0, stream>>>(w1, w1t, D_, FF_);
    transpose_cvt<<<dim3(FF_ / 64, D_ / 64, E_), 256, 0, stream>>>(w3, w3t, D_, FF_);
    transpose_cvt<<<dim3(D_ / 64, FF_ / 64, E_), 256, 0, stream>>>(w2, w2t, FF_, D_);

    gemm1_kernel<<<dim3(32, 4, 16), 512, 65536, stream>>>(hidden_bf, w1t, w3t, slot_token, counts, hbuf);
    gemm2_kernel<<<dim3(4, 8, 16), 512, 49152, stream>>>(hbuf, w2t, slot_token, counts, maxp, out);
    combine_dropped<<<B_ * S_, 256, 0, stream>>>(hidden, pos, maxp, out);
}